// Round 14
// baseline (235.205 us; speedup 1.0000x reference)
//
#include <hip/hip_runtime.h>
#include <float.h>

// Quantize: z [8,4096,512] f32, embed_w [512,128] f32, GROUPS=4
// flat = z.reshape(131072,128); dist to 512 codes; argmin; gather; MSE scalar.
// d_out (f32): z_q_st [16777216], diff [1], ind [131072] (as float).
//
// r14 = r6 fused champion with a pipelined scan loop:
//  - fp16-hi codebook (128 KB) resident in LDS, one DMA, 16 waves x 32 rows
//  - inner loop: uint4 (ds_read_b128-guaranteed) B-frag loads, explicit
//    2-tile register double-buffer (loads run 2 tiles ahead), cinit prefetched
//  - rows with top-2 score margin < TAU_A re-solved EXACTLY in fp64
//    (block-distributed worklist) => exact argmin indices

typedef _Float16 half8 __attribute__((ext_vector_type(8)));
typedef __attribute__((ext_vector_type(4))) float f32x4;

constexpr int Dn = 128;
constexpr int K  = 512;
constexpr long long Mrows = 131072;
constexpr int RPW   = 32;                    // rows per wave
constexpr int WAVES = 16;                    // waves per block (1024 threads)
constexpr int RPB   = RPW * WAVES;           // 512 rows per block
constexpr int NBLK  = (int)(Mrows / RPB);    // 256
constexpr float TAU_A = 0.05f;               // score-margin for exact re-solve

constexpr size_t ZQ_SIZE  = (size_t)Mrows * Dn;
constexpr size_t DIFF_OFF = ZQ_SIZE;
constexpr size_t IND_OFF  = ZQ_SIZE + 1;

__device__ inline void gload_lds16(const void* g, void* l) {
    __builtin_amdgcn_global_load_lds(
        (const __attribute__((address_space(1))) unsigned int*)g,
        (__attribute__((address_space(3))) unsigned int*)l,
        16, 0, 0);
}

// W -> fp16 hi, XOR-swizzled granule order (granule g of code stored at slot
// g ^ (code&7)); also wn2 = -0.5*||w||^2 (f32) and wn64 = ||w||^2 (f64).
__global__ void prep_kernel(const float* __restrict__ W,
                            unsigned short* __restrict__ Wp,
                            float* __restrict__ wn2,
                            double* __restrict__ wn64) {
    int t = blockIdx.x * 256 + threadIdx.x;  // 0..8191 (512 codes * 16 granules)
    int code = t >> 4;
    int g    = t & 15;
    const float* src = W + (size_t)code * Dn + g * 8;
    float4 a = *(const float4*)src;
    float4 b = *(const float4*)(src + 4);
    float vv[8] = {a.x, a.y, a.z, a.w, b.x, b.y, b.z, b.w};
    half8 hv;
    double s2 = 0.0;
    #pragma unroll
    for (int j = 0; j < 8; ++j) {
        hv[j] = (_Float16)vv[j];
        s2 += (double)vv[j] * (double)vv[j];
    }
    *(half8*)((char*)Wp + (size_t)code * 256 + ((g ^ (code & 7)) << 4)) = hv;
    s2 += __shfl_xor(s2, 1);
    s2 += __shfl_xor(s2, 2);
    s2 += __shfl_xor(s2, 4);
    s2 += __shfl_xor(s2, 8);
    if (g == 0) {
        wn2[code]  = (float)(-0.5 * s2);
        wn64[code] = s2;
    }
}

__global__ __launch_bounds__(1024, 4) void vq_main(
        const float* __restrict__ Z, const float* __restrict__ W,
        const unsigned short* __restrict__ Wp, const float* __restrict__ wn2,
        const double* __restrict__ wn64,
        float* __restrict__ out, double* __restrict__ diffsum) {
    __shared__ __align__(16) char Wlds[131072];   // full codebook, fp16 hi, swizzled
    __shared__ float wn2_s[K];
    __shared__ float xn_s[RPB];
    __shared__ int   sIdx[RPB];
    __shared__ int   flagList[RPB];
    __shared__ int   flagN;
    __shared__ float wpart[WAVES];

    const int tid  = threadIdx.x;
    const int w    = tid >> 6;
    const int lane = tid & 63;
    const int lm   = lane & 15;        // A row / B col within 16-tile
    const int lg   = lane >> 4;        // k-block (0..3)
    const size_t row0 = (size_t)blockIdx.x * RPB;

    if (tid == 0) flagN = 0;

    // ---- codebook DMA: 128 KB once, linear dest (pre-swizzled src) ----
    {
        const char* gsrc = (const char*)Wp;
        #pragma unroll
        for (int it = 0; it < 8; ++it) {
            const int gbase = it * 1024 + w * 64;            // wave-uniform base
            gload_lds16(gsrc + (size_t)(gbase + lane) * 16, Wlds + (size_t)gbase * 16);
        }
    }
    if (tid < K) wn2_s[tid] = wn2[tid];

    // ---- X fragments (fp16) + exact row norms (overlap the DMA) ----
    half8 ah[2][4];                     // [16-row tile][ks]
    #pragma unroll
    for (int r = 0; r < 2; ++r) {
        const size_t grow = row0 + (size_t)w * RPW + r * 16 + lm;
        float s2 = 0.f;
        #pragma unroll
        for (int ks = 0; ks < 4; ++ks) {
            const float* xp = Z + grow * Dn + ks * 32 + lg * 8;
            float4 x0 = *(const float4*)xp;
            float4 x1 = *(const float4*)(xp + 4);
            float xv[8] = {x0.x, x0.y, x0.z, x0.w, x1.x, x1.y, x1.z, x1.w};
            #pragma unroll
            for (int j = 0; j < 8; ++j) {
                ah[r][ks][j] = (_Float16)xv[j];
                s2 += xv[j] * xv[j];
            }
        }
        s2 += __shfl_xor(s2, 16);
        s2 += __shfl_xor(s2, 32);      // full ||x||^2 for row grow
        if (lg == 0) xn_s[w * RPW + r * 16 + lm] = s2;
    }

    float m1[2][4], m2[2][4];
    int   i1[2][4];
    #pragma unroll
    for (int r = 0; r < 2; ++r)
        #pragma unroll
        for (int j = 0; j < 4; ++j) { m1[r][j] = -FLT_MAX; m2[r][j] = -FLT_MAX; i1[r][j] = 0; }

    asm volatile("s_waitcnt vmcnt(0)" ::: "memory");
    __syncthreads();                   // B1: codebook + wn2 + flagN resident

    // ---- main scan: 32 B-tiles, uint4 b128 reads, 2-tile reg double-buffer ----
    {
        const uint4* __restrict__ Wl4 = (const uint4*)Wlds;

        #define LOADB(B, CIN, T) do {                                      \
            const int codeL_ = (T) * 16 + lm;                              \
            const int baseL_ = codeL_ * 16;                                \
            const int xL_    = codeL_ & 7;                                 \
            B[0] = Wl4[baseL_ + ((lg     ) ^ xL_)];                        \
            B[1] = Wl4[baseL_ + ((lg +  4) ^ xL_)];                        \
            B[2] = Wl4[baseL_ + ((lg +  8) ^ xL_)];                        \
            B[3] = Wl4[baseL_ + ((lg + 12) ^ xL_)];                        \
            CIN  = wn2_s[codeL_];                                          \
        } while (0)

        #define COMP(B, CIN, T) do {                                       \
            const int codeC_ = (T) * 16 + lm;                              \
            f32x4 acc0 = (f32x4){CIN, CIN, CIN, CIN};                      \
            f32x4 acc1 = acc0;                                             \
            half8 hb_;                                                     \
            hb_ = __builtin_bit_cast(half8, B[0]);                         \
            acc0 = __builtin_amdgcn_mfma_f32_16x16x32_f16(ah[0][0], hb_, acc0, 0, 0, 0); \
            acc1 = __builtin_amdgcn_mfma_f32_16x16x32_f16(ah[1][0], hb_, acc1, 0, 0, 0); \
            hb_ = __builtin_bit_cast(half8, B[1]);                         \
            acc0 = __builtin_amdgcn_mfma_f32_16x16x32_f16(ah[0][1], hb_, acc0, 0, 0, 0); \
            acc1 = __builtin_amdgcn_mfma_f32_16x16x32_f16(ah[1][1], hb_, acc1, 0, 0, 0); \
            hb_ = __builtin_bit_cast(half8, B[2]);                         \
            acc0 = __builtin_amdgcn_mfma_f32_16x16x32_f16(ah[0][2], hb_, acc0, 0, 0, 0); \
            acc1 = __builtin_amdgcn_mfma_f32_16x16x32_f16(ah[1][2], hb_, acc1, 0, 0, 0); \
            hb_ = __builtin_bit_cast(half8, B[3]);                         \
            acc0 = __builtin_amdgcn_mfma_f32_16x16x32_f16(ah[0][3], hb_, acc0, 0, 0, 0); \
            acc1 = __builtin_amdgcn_mfma_f32_16x16x32_f16(ah[1][3], hb_, acc1, 0, 0, 0); \
            _Pragma("unroll")                                               \
            for (int j = 0; j < 4; ++j) {                                   \
                float a0 = acc0[j];                                         \
                m2[0][j] = __builtin_amdgcn_fmed3f(a0, m1[0][j], m2[0][j]); \
                bool g0 = a0 > m1[0][j];                                    \
                m1[0][j] = fmaxf(m1[0][j], a0);                             \
                i1[0][j] = g0 ? codeC_ : i1[0][j];                          \
                float a1 = acc1[j];                                         \
                m2[1][j] = __builtin_amdgcn_fmed3f(a1, m1[1][j], m2[1][j]); \
                bool g1 = a1 > m1[1][j];                                    \
                m1[1][j] = fmaxf(m1[1][j], a1);                             \
                i1[1][j] = g1 ? codeC_ : i1[1][j];                          \
            }                                                               \
        } while (0)

        uint4 bA[4], bB[4];
        float cA, cB;
        LOADB(bA, cA, 0);
        LOADB(bB, cB, 1);
        #pragma unroll 4
        for (int t = 0; t < 32; t += 2) {
            COMP(bA, cA, t);
            LOADB(bA, cA, (t + 2) & 31);   // wraps harmlessly on last trip
            COMP(bB, cB, t + 1);
            LOADB(bB, cB, (t + 3) & 31);
        }
        #undef LOADB
        #undef COMP
    }

    // ---- reduce (m1, idx, m2) across the 16 col-lanes ----
    #pragma unroll
    for (int sft = 1; sft < 16; sft <<= 1) {
        #pragma unroll
        for (int r = 0; r < 2; ++r) {
            #pragma unroll
            for (int j = 0; j < 4; ++j) {
                float o1 = __shfl_xor(m1[r][j], sft);
                float o2 = __shfl_xor(m2[r][j], sft);
                int   oi = __shfl_xor(i1[r][j], sft);
                if (o1 > m1[r][j] || (o1 == m1[r][j] && oi < i1[r][j])) {
                    m2[r][j] = fmaxf(m1[r][j], o2);
                    m1[r][j] = o1;
                    i1[r][j] = oi;
                } else {
                    m2[r][j] = fmaxf(m2[r][j], o1);
                }
            }
        }
    }

    float psum = 0.f;
    if (lm == 0) {
        #pragma unroll
        for (int r = 0; r < 2; ++r) {
            #pragma unroll
            for (int j = 0; j < 4; ++j) {
                const int row = w * RPW + r * 16 + lg * 4 + j;   // C row = lg*4 + reg
                sIdx[row] = i1[r][j];
                psum += xn_s[row] - 2.f * m1[r][j];              // dist^2 = ||x||^2 - 2a
                if (m1[r][j] - m2[r][j] < TAU_A) {
                    int pos = atomicAdd(&flagN, 1);
                    flagList[pos] = row;
                }
            }
        }
    }
    __syncthreads();                   // B2: sIdx + worklist complete

    // ---- exact refinement, block-distributed over the worklist ----
    {
        const int nf = flagN;
        const int cg    = lane >> 3;           // code subgroup 0..7
        const int dbase = (lane & 7) * 16;     // 16-dim slice per lane
        for (int fi = w; fi < nf; fi += WAVES) {
            const int rr = flagList[fi];
            const float* xp = Z + (row0 + rr) * Dn + dbase;
            double xd[16];
            #pragma unroll
            for (int q = 0; q < 16; q += 4) {
                float4 v = *(const float4*)(xp + q);
                xd[q] = v.x; xd[q+1] = v.y; xd[q+2] = v.z; xd[q+3] = v.w;
            }
            double best = 1e300; int bi = 0;
            for (int cb = 0; cb < 64; ++cb) {
                const int c = cb * 8 + cg;
                const float* wp = W + (size_t)c * Dn + dbase;
                double s = 0.0;
                #pragma unroll
                for (int q = 0; q < 16; q += 4) {
                    float4 wv = *(const float4*)(wp + q);
                    s += xd[q]   * (double)wv.x;
                    s += xd[q+1] * (double)wv.y;
                    s += xd[q+2] * (double)wv.z;
                    s += xd[q+3] * (double)wv.w;
                }
                s += __shfl_xor(s, 1);
                s += __shfl_xor(s, 2);
                s += __shfl_xor(s, 4);         // all 8 lanes of group hold dot(c)
                const double sc = wn64[c] - 2.0 * s;   // dist^2 - ||x||^2 (exact)
                if (sc < best) { best = sc; bi = c; } // ascending c => min-idx tiebreak
            }
            #pragma unroll
            for (int sft = 8; sft < 64; sft <<= 1) {
                double ob = __shfl_xor(best, sft);
                int    ok = __shfl_xor(bi, sft);
                if (ob < best || (ob == best && ok < bi)) { best = ob; bi = ok; }
            }
            if (lane == 0) sIdx[rr] = bi;
        }
    }
    __syncthreads();                   // B3: refined sIdx visible

    // ---- epilogue: gather W[ind], store z_q_st, ind, diff ----
    #pragma unroll
    for (int it = 0; it < 16; ++it) {
        int f4i = lane + it * 64;              // 0..1023
        int rl  = f4i >> 5, cq = f4i & 31;     // 32 rows x 32 float4
        int ind = sIdx[w * RPW + rl];
        float4 wv = ((const float4*)(W + (size_t)ind * Dn))[cq];
        ((float4*)(out + (row0 + w * RPW + rl) * Dn))[cq] = wv;
    }
    if (lane < RPW)
        out[IND_OFF + row0 + w * RPW + lane] = (float)sIdx[w * RPW + lane];

    #pragma unroll
    for (int sft = 1; sft < 64; sft <<= 1) psum += __shfl_xor(psum, sft);
    if (lane == 0) wpart[w] = psum;
    __syncthreads();
    if (tid == 0) {
        double t = 0.0;
        #pragma unroll
        for (int i = 0; i < WAVES; ++i) t += (double)wpart[i];
        atomicAdd(diffsum, t);
    }
}

__global__ void diff_kernel(const double* __restrict__ diffsum, float* __restrict__ out) {
    if (threadIdx.x == 0 && blockIdx.x == 0) {
        // KLD_SCALE * (COMMITMENT_COST + 1) * mean = 12.5 * mean
        out[DIFF_OFF] = (float)(12.5 * diffsum[0] / (double)ZQ_SIZE);
    }
}

extern "C" void kernel_launch(void* const* d_in, const int* in_sizes, int n_in,
                              void* d_out, int out_size, void* d_ws, size_t ws_size,
                              hipStream_t stream) {
    (void)in_sizes; (void)n_in; (void)out_size; (void)ws_size;
    const float* Z = (const float*)d_in[0];
    const float* W = (const float*)d_in[1];
    float* out = (float*)d_out;
    // ws: [0,8) diffsum; [64,2112) wn2 f32[512]; [2112,6208) wn64 f64[512];
    //     [8192, +128KB) Wp fp16 swizzled
    double* diffsum = (double*)d_ws;
    float*  wn2  = (float*)((char*)d_ws + 64);
    double* wn64 = (double*)((char*)d_ws + 2112);
    unsigned short* Wp = (unsigned short*)((char*)d_ws + 8192);

    hipMemsetAsync(d_ws, 0, 16, stream);
    prep_kernel<<<32, 256, 0, stream>>>(W, Wp, wn2, wn64);
    vq_main<<<NBLK, 1024, 0, stream>>>(Z, W, Wp, wn2, wn64, out, diffsum);
    diff_kernel<<<1, 64, 0, stream>>>(diffsum, out);
}